// Round 1
// baseline (161.598 us; speedup 1.0000x reference)
//
#include <hip/hip_runtime.h>
#include <math.h>

#define NB 8
#define NH 8
#define SEQ 512
#define DK 64
#define NC 5
#define D_IN 262144   // 8*512*64 per batch
#define OUT_SCORE (NB*NH*SEQ*SEQ)   // 2097152

// ---------------- Kernel A: ck[b][c] = sum_i K[b*D_IN+i] * Wp[i*5+c] ----------------
__global__ __launch_bounds__(256) void proj_kernel(const float* __restrict__ K,
                                                   const float* __restrict__ Wp,
                                                   float* __restrict__ ck) {
  const int CHUNK = D_IN / 128;   // 2048 (gridDim.x == 128)
  int base = blockIdx.x * CHUNK;
  float acc[NB][NC];
#pragma unroll
  for (int b = 0; b < NB; ++b)
#pragma unroll
    for (int c = 0; c < NC; ++c) acc[b][c] = 0.f;

  for (int it = 0; it < CHUNK / 256; ++it) {
    int i = base + it * 256 + threadIdx.x;
    float w[NC];
#pragma unroll
    for (int c = 0; c < NC; ++c) w[c] = Wp[i * NC + c];
#pragma unroll
    for (int b = 0; b < NB; ++b) {
      float kv = K[b * D_IN + i];
#pragma unroll
      for (int c = 0; c < NC; ++c) acc[b][c] = fmaf(kv, w[c], acc[b][c]);
    }
  }

  __shared__ float red[4][NB * NC];
  int wave = threadIdx.x >> 6;
  int lane = threadIdx.x & 63;
#pragma unroll
  for (int bc = 0; bc < NB * NC; ++bc) {
    float v = acc[bc / NC][bc % NC];
#pragma unroll
    for (int off = 32; off > 0; off >>= 1) v += __shfl_down(v, off);
    if (lane == 0) red[wave][bc] = v;
  }
  __syncthreads();
  if (threadIdx.x < NB * NC) {
    float s = red[0][threadIdx.x] + red[1][threadIdx.x] +
              red[2][threadIdx.x] + red[3][threadIdx.x];
    atomicAdd(&ck[threadIdx.x], s);
  }
}

// ---------------- Kernel B: stats, loss, means ----------------
__global__ __launch_bounds__(256) void small_kernel(
    const float* __restrict__ K, const float* __restrict__ ck_raw,
    const float* __restrict__ bp, const float* __restrict__ Wq,
    const float* __restrict__ bq, const float* __restrict__ Wk,
    const float* __restrict__ bk, float* __restrict__ means,
    float* __restrict__ loss_out) {
  __shared__ float cq[NB][NC], ckk[NB][NC], ce_sh[NB];
  __shared__ int inds[NB];
  int t = threadIdx.x;
  if (t < NB) {
    float cp[NC], zq[NC], zk[NC];
#pragma unroll
    for (int c = 0; c < NC; ++c) cp[c] = ck_raw[t * NC + c] + bp[c];
#pragma unroll
    for (int c = 0; c < NC; ++c) { zq[c] = bq[c]; zk[c] = bk[c]; }
#pragma unroll
    for (int j = 0; j < NC; ++j)
#pragma unroll
      for (int c = 0; c < NC; ++c) {
        zq[c] = fmaf(cp[j], Wq[j * NC + c], zq[c]);
        zk[c] = fmaf(cp[j], Wk[j * NC + c], zk[c]);
      }
    // softmax(zq) -> p
    float m = zq[0];
#pragma unroll
    for (int c = 1; c < NC; ++c) m = fmaxf(m, zq[c]);
    float e[NC], s = 0.f;
#pragma unroll
    for (int c = 0; c < NC; ++c) { e[c] = expf(zq[c] - m); s += e[c]; }
    float inv = 1.f / s;
    float p[NC];
#pragma unroll
    for (int c = 0; c < NC; ++c) { p[c] = e[c] * inv; cq[t][c] = p[c]; }
    // argmax (first max)
    int am = 0; float bv = p[0];
#pragma unroll
    for (int c = 1; c < NC; ++c) if (p[c] > bv) { bv = p[c]; am = c; }
    inds[t] = am;
    // ce_b = -sum p*(p - logsumexp(p))
    float se = 0.f;
#pragma unroll
    for (int c = 0; c < NC; ++c) se += expf(p[c] - bv);
    float lse = bv + logf(se);
    float ceb = 0.f;
#pragma unroll
    for (int c = 0; c < NC; ++c) ceb -= p[c] * (p[c] - lse);
    ce_sh[t] = ceb;
    // softmax(zk)
    m = zk[0];
#pragma unroll
    for (int c = 1; c < NC; ++c) m = fmaxf(m, zk[c]);
    s = 0.f;
#pragma unroll
    for (int c = 0; c < NC; ++c) { e[c] = expf(zk[c] - m); s += e[c]; }
    inv = 1.f / s;
#pragma unroll
    for (int c = 0; c < NC; ++c) ckk[t][c] = e[c] * inv;
  }
  __syncthreads();
  if (t == 0) {
    float mu[NC];
#pragma unroll
    for (int c = 0; c < NC; ++c) {
      float sm = 0.f;
      for (int b = 0; b < NB; ++b) sm += cq[b][c];
      mu[c] = sm * 0.125f;
    }
    float loss_lp = 0.f;
#pragma unroll
    for (int c = 0; c < NC; ++c) {
      float sm = 0.f;
      for (int b = 0; b < NB; ++b) sm += ckk[b][c];
      float mk = sm * 0.125f;
      float var = 0.f;
      for (int b = 0; b < NB; ++b) {
        float d = ckk[b][c] - mk;
        var += d * d;
      }
      var *= (1.f / 7.f);                 // ddof=1
      float sd = sqrtf(var);
      float sigma = log1pf(expf(sd));     // softplus
      float ls = logf(sigma);
      for (int b = 0; b < NB; ++b) {
        float z = (ckk[b][c] - mu[c]) / sigma;
        loss_lp += -0.5f * z * z - ls - 0.91893853320467274f;  // 0.5*log(2pi)
      }
    }
    float ce = 0.f;
    for (int b = 0; b < NB; ++b) ce += ce_sh[b];
    ce *= 0.125f;
    loss_out[0] = -(loss_lp / 40.f) + ce;
  }
  __syncthreads();
  // means[c][j] = (1/8) * sum_{b: inds[b] != c+1} K[b*D_IN + j],  j<512
  for (int idx = t; idx < NC * 512; idx += 256) {
    int c = idx >> 9, j = idx & 511;
    float sm = 0.f;
#pragma unroll
    for (int b = 0; b < NB; ++b)
      if (inds[b] != c + 1) sm += K[b * D_IN + j];
    means[idx] = sm * 0.125f;
  }
}

// ---------------- Kernel C: fused QK^T * scale, max with cluster scores ----------------
// cm[b,h,c2,k,d] == means[(5h+c2)>>3, 64*(k&7)+d]  (flat-reshape index algebra)
__global__ __launch_bounds__(256) void score_kernel(const float* __restrict__ Q,
                                                    const float* __restrict__ K,
                                                    const float* __restrict__ means,
                                                    float* __restrict__ out) {
  __shared__ float Qs[64][68];   // [d][q], pad->16B-aligned float4 rows
  __shared__ float Ks[64][68];   // [d][k]
  __shared__ float qc[64][8];    // per-q, per-(k&7) cluster-score max

  int bh = blockIdx.x;           // 0..63 : b*8+h
  int qt = blockIdx.y;           // 0..7
  int h = bh & 7;
  int tid = threadIdx.x;

  // load Q tile transposed
  const float* Qg = Q + (size_t)(bh * SEQ + qt * 64) * DK;
#pragma unroll
  for (int i = 0; i < 4; ++i) {
    int f = tid + 256 * i;            // 0..1023 float4s
    int q = f >> 4;
    int d0 = (f & 15) << 2;
    float4 v = *(const float4*)(Qg + q * DK + d0);
    Qs[d0 + 0][q] = v.x; Qs[d0 + 1][q] = v.y;
    Qs[d0 + 2][q] = v.z; Qs[d0 + 3][q] = v.w;
  }
  __syncthreads();

  // qc[q][r] = 0.125 * max_{c in [cmin,cmax]} dot(Qtile[q], means[c][64r:64r+64])
  int cmin = (5 * h) >> 3;
  int cmax = (5 * h + 4) >> 3;
  for (int task = tid; task < 512; task += 256) {
    int q = task & 63, r = task >> 6;
    const float* m0 = means + cmin * 512 + r * 64;
    const float* m1 = means + cmax * 512 + r * 64;
    float s0 = 0.f, s1 = 0.f;
#pragma unroll
    for (int d = 0; d < 64; ++d) {
      float qv = Qs[d][q];
      s0 = fmaf(qv, m0[d], s0);
      s1 = fmaf(qv, m1[d], s1);
    }
    qc[q][r] = fmaxf(s0, s1) * 0.125f;
  }

  int ty = tid >> 4, tx = tid & 15;
  for (int kt = 0; kt < 8; ++kt) {
    __syncthreads();   // prev compute done (and qc written, first iter)
    const float* Kg = K + (size_t)(bh * SEQ + kt * 64) * DK;
#pragma unroll
    for (int i = 0; i < 4; ++i) {
      int f = tid + 256 * i;
      int k = f >> 4;
      int d0 = (f & 15) << 2;
      float4 v = *(const float4*)(Kg + k * DK + d0);
      Ks[d0 + 0][k] = v.x; Ks[d0 + 1][k] = v.y;
      Ks[d0 + 2][k] = v.z; Ks[d0 + 3][k] = v.w;
    }
    __syncthreads();

    float acc[4][4];
#pragma unroll
    for (int i = 0; i < 4; ++i)
#pragma unroll
      for (int j = 0; j < 4; ++j) acc[i][j] = 0.f;

#pragma unroll 8
    for (int d = 0; d < 64; ++d) {
      float4 a = *(const float4*)&Qs[d][ty * 4];
      float4 bb = *(const float4*)&Ks[d][tx * 4];
      float av[4] = {a.x, a.y, a.z, a.w};
      float bv[4] = {bb.x, bb.y, bb.z, bb.w};
#pragma unroll
      for (int i = 0; i < 4; ++i)
#pragma unroll
        for (int j = 0; j < 4; ++j) acc[i][j] = fmaf(av[i], bv[j], acc[i][j]);
    }

#pragma unroll
    for (int i = 0; i < 4; ++i) {
      int q = ty * 4 + i;
      float4 o;
      float* op = (float*)&o;
#pragma unroll
      for (int j = 0; j < 4; ++j)
        op[j] = fmaxf(acc[i][j] * 0.125f, qc[q][(tx * 4 + j) & 7]);
      *(float4*)(out + (size_t)(bh * SEQ + qt * 64 + q) * SEQ + kt * 64 + tx * 4) = o;
    }
  }
}

extern "C" void kernel_launch(void* const* d_in, const int* in_sizes, int n_in,
                              void* d_out, int out_size, void* d_ws, size_t ws_size,
                              hipStream_t stream) {
  const float* Q  = (const float*)d_in[0];
  const float* K  = (const float*)d_in[1];
  const float* Wp = (const float*)d_in[2];
  const float* bp = (const float*)d_in[3];
  const float* Wq = (const float*)d_in[4];
  const float* bq = (const float*)d_in[5];
  const float* Wk = (const float*)d_in[6];
  const float* bk = (const float*)d_in[7];
  float* out = (float*)d_out;

  float* ck = (float*)d_ws;          // 40 floats (atomic accum)
  float* means = ck + 64;            // 5*512 floats

  hipMemsetAsync(ck, 0, NB * NC * sizeof(float), stream);
  proj_kernel<<<128, 256, 0, stream>>>(K, Wp, ck);
  small_kernel<<<1, 256, 0, stream>>>(K, ck, bp, Wq, bq, Wk, bk, means,
                                      out + OUT_SCORE);
  dim3 grid(64, 8);
  score_kernel<<<grid, 256, 0, stream>>>(Q, K, means, out);
}

// Round 2
// 147.166 us; speedup vs baseline: 1.0981x; 1.0981x over previous
//
#include <hip/hip_runtime.h>
#include <math.h>

#define NB 8
#define NH 8
#define SEQ 512
#define DK 64
#define NC 5
#define D_IN 262144   // 8*512*64 per batch
#define OUT_SCORE (NB*NH*SEQ*SEQ)   // 16777216

typedef short short8 __attribute__((ext_vector_type(8)));
typedef float f32x16 __attribute__((ext_vector_type(16)));

// fp32 -> bf16 (RTNE), bit pattern in a short
__device__ __forceinline__ short f2bf(float f) {
  unsigned u = __float_as_uint(f);
  u += 0x7fffu + ((u >> 16) & 1u);
  return (short)(u >> 16);
}
__device__ __forceinline__ short8 pack8(float4 a, float4 b) {
  short8 r;
  r[0] = f2bf(a.x); r[1] = f2bf(a.y); r[2] = f2bf(a.z); r[3] = f2bf(a.w);
  r[4] = f2bf(b.x); r[5] = f2bf(b.y); r[6] = f2bf(b.z); r[7] = f2bf(b.w);
  return r;
}

// ---------------- Kernel A: ck[b][c] = sum_i K[b*D_IN+i] * Wp[i*5+c] ----------------
// 256 blocks x 256 threads; each thread owns one float4-index (65536 total).
__global__ __launch_bounds__(256) void proj_kernel(const float* __restrict__ K,
                                                   const float* __restrict__ Wp,
                                                   float* __restrict__ ck) {
  int i4 = blockIdx.x * 256 + threadIdx.x;   // float4 index over D_IN
  const float4* Wp4 = (const float4*)Wp;
  float w[20];
#pragma unroll
  for (int t = 0; t < 5; ++t) {
    float4 v = Wp4[i4 * 5 + t];
    w[4*t+0] = v.x; w[4*t+1] = v.y; w[4*t+2] = v.z; w[4*t+3] = v.w;
  }
  float acc[NB][NC];
#pragma unroll
  for (int b = 0; b < NB; ++b)
#pragma unroll
    for (int c = 0; c < NC; ++c) acc[b][c] = 0.f;
#pragma unroll
  for (int b = 0; b < NB; ++b) {
    float4 kv = ((const float4*)(K + (size_t)b * D_IN))[i4];
    float ke[4] = {kv.x, kv.y, kv.z, kv.w};
#pragma unroll
    for (int e = 0; e < 4; ++e)
#pragma unroll
      for (int c = 0; c < NC; ++c)
        acc[b][c] = fmaf(ke[e], w[5*e + c], acc[b][c]);
  }

  __shared__ float red[4][NB * NC];
  int wave = threadIdx.x >> 6;
  int lane = threadIdx.x & 63;
#pragma unroll
  for (int bc = 0; bc < NB * NC; ++bc) {
    float v = acc[bc / NC][bc % NC];
#pragma unroll
    for (int off = 32; off > 0; off >>= 1) v += __shfl_down(v, off);
    if (lane == 0) red[wave][bc] = v;
  }
  __syncthreads();
  if (threadIdx.x < NB * NC) {
    float s = red[0][threadIdx.x] + red[1][threadIdx.x] +
              red[2][threadIdx.x] + red[3][threadIdx.x];
    atomicAdd(&ck[threadIdx.x], s);
  }
}

// ---------------- Kernel B: stats, loss, means ----------------
__global__ __launch_bounds__(256) void small_kernel(
    const float* __restrict__ K, const float* __restrict__ ck_raw,
    const float* __restrict__ bp, const float* __restrict__ Wq,
    const float* __restrict__ bq, const float* __restrict__ Wk,
    const float* __restrict__ bk, float* __restrict__ means,
    float* __restrict__ loss_out) {
  __shared__ float cq[NB][NC], ckk[NB][NC], ce_sh[NB];
  __shared__ int inds[NB];
  int t = threadIdx.x;
  if (t < NB) {
    float cp[NC], zq[NC], zk[NC];
#pragma unroll
    for (int c = 0; c < NC; ++c) cp[c] = ck_raw[t * NC + c] + bp[c];
#pragma unroll
    for (int c = 0; c < NC; ++c) { zq[c] = bq[c]; zk[c] = bk[c]; }
#pragma unroll
    for (int j = 0; j < NC; ++j)
#pragma unroll
      for (int c = 0; c < NC; ++c) {
        zq[c] = fmaf(cp[j], Wq[j * NC + c], zq[c]);
        zk[c] = fmaf(cp[j], Wk[j * NC + c], zk[c]);
      }
    float m = zq[0];
#pragma unroll
    for (int c = 1; c < NC; ++c) m = fmaxf(m, zq[c]);
    float e[NC], s = 0.f;
#pragma unroll
    for (int c = 0; c < NC; ++c) { e[c] = expf(zq[c] - m); s += e[c]; }
    float inv = 1.f / s;
    float p[NC];
#pragma unroll
    for (int c = 0; c < NC; ++c) { p[c] = e[c] * inv; cq[t][c] = p[c]; }
    int am = 0; float bv = p[0];
#pragma unroll
    for (int c = 1; c < NC; ++c) if (p[c] > bv) { bv = p[c]; am = c; }
    inds[t] = am;
    float se = 0.f;
#pragma unroll
    for (int c = 0; c < NC; ++c) se += expf(p[c] - bv);
    float lse = bv + logf(se);
    float ceb = 0.f;
#pragma unroll
    for (int c = 0; c < NC; ++c) ceb -= p[c] * (p[c] - lse);
    ce_sh[t] = ceb;
    m = zk[0];
#pragma unroll
    for (int c = 1; c < NC; ++c) m = fmaxf(m, zk[c]);
    s = 0.f;
#pragma unroll
    for (int c = 0; c < NC; ++c) { e[c] = expf(zk[c] - m); s += e[c]; }
    inv = 1.f / s;
#pragma unroll
    for (int c = 0; c < NC; ++c) ckk[t][c] = e[c] * inv;
  }
  __syncthreads();
  if (t == 0) {
    float mu[NC];
#pragma unroll
    for (int c = 0; c < NC; ++c) {
      float sm = 0.f;
      for (int b = 0; b < NB; ++b) sm += cq[b][c];
      mu[c] = sm * 0.125f;
    }
    float loss_lp = 0.f;
#pragma unroll
    for (int c = 0; c < NC; ++c) {
      float sm = 0.f;
      for (int b = 0; b < NB; ++b) sm += ckk[b][c];
      float mk = sm * 0.125f;
      float var = 0.f;
      for (int b = 0; b < NB; ++b) {
        float d = ckk[b][c] - mk;
        var += d * d;
      }
      var *= (1.f / 7.f);                 // ddof=1
      float sd = sqrtf(var);
      float sigma = log1pf(expf(sd));     // softplus
      float ls = logf(sigma);
      for (int b = 0; b < NB; ++b) {
        float z = (ckk[b][c] - mu[c]) / sigma;
        loss_lp += -0.5f * z * z - ls - 0.91893853320467274f;
      }
    }
    float ce = 0.f;
    for (int b = 0; b < NB; ++b) ce += ce_sh[b];
    ce *= 0.125f;
    loss_out[0] = -(loss_lp / 40.f) + ce;
  }
  __syncthreads();
  // means[c][j] = (1/8) * sum_{b: inds[b] != c+1} K[b*D_IN + j],  j<512
  for (int idx = t; idx < NC * 512; idx += 256) {
    int c = idx >> 9, j = idx & 511;
    float sm = 0.f;
#pragma unroll
    for (int b = 0; b < NB; ++b)
      if (inds[b] != c + 1) sm += K[(size_t)b * D_IN + j];
    means[idx] = sm * 0.125f;
  }
}

// ---------------- Kernel C: bf16-MFMA QK^T fused with cluster-score max ------------
// cm[b,h,c2,k,d] == means[(5h+c2)>>3, 64*(k&7)+d]; only {cmin,cmax} distinct.
// Block: 256 thr (4 waves, 2x2), tile 128q x 128k, grid (64 bh, 4 qt, 4 kt).
// No LDS: fragments loaded directly from global (32B-contiguous per lane).
// A frag (32x32x16): element[m=lane&31][k=(lane>>5)*8+j]; B symmetric.
// C/D: col=lane&31, row=(reg&3)+8*(reg>>2)+4*(lane>>5)  [HW-verified].
__global__ __launch_bounds__(256) void score_kernel(const float* __restrict__ Q,
                                                    const float* __restrict__ K,
                                                    const float* __restrict__ means,
                                                    float* __restrict__ out) {
  const int bh = blockIdx.x;
  const int h  = bh & 7;
  const int qblk = blockIdx.y << 7;
  const int kblk = blockIdx.z << 7;
  const int tid = threadIdx.x;
  const int w = tid >> 6, lane = tid & 63;
  const int lo5 = lane & 31, hi = lane >> 5;
  const int wq = ((w >> 1) << 6), wk = ((w & 1) << 6);

  const float* Qb = Q + (size_t)bh * (SEQ * DK);
  const float* Kb = K + (size_t)bh * (SEQ * DK);

  // ---- A fragments for this wave's two 32-row groups, all 4 K-steps ----
  short8 afrag[2][4];
#pragma unroll
  for (int i = 0; i < 2; ++i)
#pragma unroll
    for (int s = 0; s < 4; ++s) {
      const float* p = Qb + (size_t)(qblk + wq + i * 32 + lo5) * DK + s * 16 + hi * 8;
      afrag[i][s] = pack8(*(const float4*)p, *(const float4*)(p + 4));
    }

  f32x16 zero;
#pragma unroll
  for (int x = 0; x < 16; ++x) zero[x] = 0.f;

  // ---- qc via MFMA: B columns n<8 -> cmin, n in [8,16) -> cmax ----
  const int cmin = (5 * h) >> 3;
  const int cmax = (5 * h + 4) >> 3;
  const int r = lo5 & 7;
  const int csel = (lo5 & 8) ? cmax : cmin;
  f32x16 aq0 = zero, aq1 = zero;
#pragma unroll
  for (int s = 0; s < 4; ++s) {
    const float* mp = means + csel * 512 + r * 64 + s * 16 + hi * 8;
    short8 bm = pack8(*(const float4*)mp, *(const float4*)(mp + 4));
    aq0 = __builtin_amdgcn_mfma_f32_32x32x16_bf16(afrag[0][s], bm, aq0, 0, 0, 0);
    aq1 = __builtin_amdgcn_mfma_f32_32x32x16_bf16(afrag[1][s], bm, aq1, 0, 0, 0);
  }
  // broadcast max(cmin,cmax) to all lanes of the same column-group r
  float qcv[2][16];
  const int sb = lane & 32;
#pragma unroll
  for (int reg = 0; reg < 16; ++reg) {
    float v0 = aq0[reg], v1 = aq1[reg];
    float a0 = __shfl(v0, sb + r),     a1 = __shfl(v1, sb + r);
    float b0 = __shfl(v0, sb + 8 + r), b1 = __shfl(v1, sb + 8 + r);
    qcv[0][reg] = fmaxf(a0, b0) * 0.125f;
    qcv[1][reg] = fmaxf(a1, b1) * 0.125f;
  }

  // ---- main QK^T ----
  f32x16 acc00 = zero, acc01 = zero, acc10 = zero, acc11 = zero;
#pragma unroll
  for (int s = 0; s < 4; ++s) {
    const float* p0 = Kb + (size_t)(kblk + wk + lo5) * DK + s * 16 + hi * 8;
    const float* p1 = Kb + (size_t)(kblk + wk + 32 + lo5) * DK + s * 16 + hi * 8;
    short8 bf0 = pack8(*(const float4*)p0, *(const float4*)(p0 + 4));
    short8 bf1 = pack8(*(const float4*)p1, *(const float4*)(p1 + 4));
    acc00 = __builtin_amdgcn_mfma_f32_32x32x16_bf16(afrag[0][s], bf0, acc00, 0, 0, 0);
    acc01 = __builtin_amdgcn_mfma_f32_32x32x16_bf16(afrag[0][s], bf1, acc01, 0, 0, 0);
    acc10 = __builtin_amdgcn_mfma_f32_32x32x16_bf16(afrag[1][s], bf0, acc10, 0, 0, 0);
    acc11 = __builtin_amdgcn_mfma_f32_32x32x16_bf16(afrag[1][s], bf1, acc11, 0, 0, 0);
  }

  // ---- epilogue: scale, fuse max(qc), store ----
  float* ob = out + (size_t)bh * (SEQ * SEQ);
  const int col0 = kblk + wk + lo5;
#pragma unroll
  for (int reg = 0; reg < 16; ++reg) {
    int rowbase = qblk + wq + (reg & 3) + ((reg >> 2) << 3) + (hi << 2);
    float q0 = qcv[0][reg], q1 = qcv[1][reg];
    ob[(size_t)(rowbase)      * SEQ + col0]      = fmaxf(acc00[reg] * 0.125f, q0);
    ob[(size_t)(rowbase)      * SEQ + col0 + 32] = fmaxf(acc01[reg] * 0.125f, q0);
    ob[(size_t)(rowbase + 32) * SEQ + col0]      = fmaxf(acc10[reg] * 0.125f, q1);
    ob[(size_t)(rowbase + 32) * SEQ + col0 + 32] = fmaxf(acc11[reg] * 0.125f, q1);
  }
}

extern "C" void kernel_launch(void* const* d_in, const int* in_sizes, int n_in,
                              void* d_out, int out_size, void* d_ws, size_t ws_size,
                              hipStream_t stream) {
  const float* Q  = (const float*)d_in[0];
  const float* K  = (const float*)d_in[1];
  const float* Wp = (const float*)d_in[2];
  const float* bp = (const float*)d_in[3];
  const float* Wq = (const float*)d_in[4];
  const float* bq = (const float*)d_in[5];
  const float* Wk = (const float*)d_in[6];
  const float* bk = (const float*)d_in[7];
  float* out = (float*)d_out;

  float* ck = (float*)d_ws;          // 64 floats (atomic accum)
  float* means = ck + 64;            // 5*512 floats

  hipMemsetAsync(ck, 0, NB * NC * sizeof(float), stream);
  proj_kernel<<<256, 256, 0, stream>>>(K, Wp, ck);
  small_kernel<<<1, 256, 0, stream>>>(K, ck, bp, Wq, bq, Wk, bk, means,
                                      out + OUT_SCORE);
  dim3 grid(64, 4, 4);
  score_kernel<<<grid, 256, 0, stream>>>(Q, K, means, out);
}